// Round 1
// baseline (1641.323 us; speedup 1.0000x reference)
//
#include <hip/hip_runtime.h>
#include <hip/hip_bf16.h>

// RetinaNet head on MI355X: implicit-GEMM bf16 MFMA convs over padded-NHWC
// activations. See analysis: compute-bound, target bf16 matrix pipe.

typedef float  f32x4 __attribute__((ext_vector_type(4)));
typedef int    i32x4 __attribute__((ext_vector_type(4)));
typedef __bf16 bfrag __attribute__((ext_vector_type(8)));
typedef __bf16 bf4   __attribute__((ext_vector_type(4)));

struct LevelD {
  int H, W, logW, logHW, P, HW, act_off, aoff, ntn, blk_start, pos_start;
};
struct Desc  { LevelD lv[6]; };
struct FPtrs { const float* f[6]; };

#define ACT_ELEMS  24735744
#define WREG_OFF   0
#define WCLS_OFF   2359296
#define WREGO_OFF  4718592
#define WCLSO_OFF  4773888
#define ACT0_OFF   4898304
#define ACT1_OFF   29634048
#define WS_ELEMS   54369792ull
#define TOTAL_ANCH 65520
#define CLS_BASE   2096640

// ---- weight prep: [CO][256ci][3][3] f32 -> [CO][t=9][256ci] bf16 ----
__global__ __launch_bounds__(256) void prep_k(const float* __restrict__ w,
                                              __bf16* __restrict__ o, int total)
{
  for (int i = blockIdx.x * 256 + threadIdx.x; i < total; i += gridDim.x * 256) {
    int co = i / 2304;
    int r  = i - co * 2304;
    int t  = r >> 8;
    int ci = r & 255;
    o[i] = (__bf16)w[((co << 8) + ci) * 9 + t];
  }
}

// ---- NCHW f32 feat -> padded NHWC bf16 (interior only; halos pre-zeroed) ----
__global__ __launch_bounds__(256) void convert_k(FPtrs fp, __bf16* __restrict__ act, Desc d)
{
  __shared__ __bf16 T[16 * 264];
  int b  = blockIdx.x;
  int p0 = b << 4;
  int li = 0;
  #pragma unroll
  for (int i = 1; i < 6; ++i) li = (p0 >= d.lv[i].pos_start) ? i : li;
  LevelD L = d.lv[li];
  int lp  = p0 - L.pos_start;
  int tid = threadIdx.x;
  // phase 1: coalesced NCHW reads (16 x-consecutive pos per 16-lane group)
  int pl = tid & 15;
  int p  = lp + pl;
  int n  = p >> L.logHW;
  int y  = (p >> L.logW) & (L.H - 1);
  int x  = p & (L.W - 1);
  const float* src = fp.f[li];
  size_t base = (size_t)n * ((size_t)L.HW << 8) + (size_t)y * L.W + x;
  int c0 = tid >> 4;
  #pragma unroll
  for (int it = 0; it < 16; ++it) {
    int c = c0 + (it << 4);
    T[pl * 264 + c] = (__bf16)src[base + (size_t)c * L.HW];
  }
  __syncthreads();
  // phase 2: c-contiguous 32B writes to padded NHWC
  int p2 = tid >> 4;
  int cc = (tid & 15) << 4;
  int pg = lp + p2;
  int n2 = pg >> L.logHW;
  int y2 = (pg >> L.logW) & (L.H - 1);
  int x2 = pg & (L.W - 1);
  __bf16* dst = act + L.act_off +
      ((size_t)((n2 * (L.H + 2) + y2 + 1) * (L.W + 2) + x2 + 1) << 8) + cc;
  i32x4 v0 = *(const i32x4*)&T[p2 * 264 + cc];
  i32x4 v1 = *(const i32x4*)&T[p2 * 264 + cc + 8];
  *(i32x4*)dst       = v0;
  *(i32x4*)(dst + 8) = v1;
}

// ---- mid conv: 256->256, +bias, ReLU, padded NHWC bf16 -> padded NHWC bf16 ----
// 128x128 tile, BK=32, 4 waves (2x2), mfma_f32_16x16x32_bf16.
__global__ __launch_bounds__(256)
void conv_mid_k(const __bf16* __restrict__ inb, __bf16* __restrict__ outb,
                const __bf16* __restrict__ wT, const float* __restrict__ bias,
                Desc d)
{
  __shared__ __bf16 Al[128 * 40];   // [co][ci] rows padded to 40 (80B stride)
  __shared__ __bf16 Bl[128 * 40];   // [pos][ci]
  int b  = blockIdx.x;
  int li = 0;
  #pragma unroll
  for (int i = 1; i < 6; ++i) li = (b >= d.lv[i].blk_start) ? i : li;
  LevelD L  = d.lv[li];
  int local = b - L.blk_start;
  int mt = local & 1;
  int nt = local >> 1;
  int m0 = mt << 7;
  int p0 = nt << 7;
  int tid  = threadIdx.x;
  int lane = tid & 63;
  int wv   = tid >> 6;
  int wm = wv >> 1, wn = wv & 1;
  int fr = lane & 15, fg = lane >> 4;
  int Wp = L.W + 2;

  // staging assignment: thread -> (row sp, ci-half sc)
  int sp = tid >> 1;
  int sc = (tid & 1) << 4;
  int p  = p0 + sp;
  bool pv = p < L.P;
  int pc = pv ? p : 0;
  int n  = pc >> L.logHW;
  int y  = (pc >> L.logW) & (L.H - 1);
  int x  = pc & (L.W - 1);
  const __bf16* bbase = inb + L.act_off + (((n * (L.H + 2) + y) * Wp + x) << 8) + sc;
  int co = m0 + sp;
  const __bf16* abase = wT + co * 2304 + sc;
  __bf16* aw = &Al[sp * 40 + sc];
  __bf16* bw = &Bl[sp * 40 + sc];

  f32x4 acc[4][4] = {};

  for (int t = 0; t < 9; ++t) {
    int ky = t / 3, kx = t - ky * 3;
    const __bf16* bt = bbase + ((ky * Wp + kx) << 8);
    const __bf16* at = abase + (t << 8);
    for (int c0 = 0; c0 < 256; c0 += 32) {
      i32x4 av0 = *(const i32x4*)(at + c0);
      i32x4 av1 = *(const i32x4*)(at + c0 + 8);
      i32x4 bv0 = {}, bv1 = {};
      if (pv) {
        bv0 = *(const i32x4*)(bt + c0);
        bv1 = *(const i32x4*)(bt + c0 + 8);
      }
      __syncthreads();
      *(i32x4*)aw       = av0;
      *(i32x4*)(aw + 8) = av1;
      *(i32x4*)bw       = bv0;
      *(i32x4*)(bw + 8) = bv1;
      __syncthreads();
      bfrag af[4], bfv[4];
      #pragma unroll
      for (int mf = 0; mf < 4; ++mf)
        af[mf] = *(const bfrag*)&Al[((wm << 6) + (mf << 4) + fr) * 40 + (fg << 3)];
      #pragma unroll
      for (int nf = 0; nf < 4; ++nf)
        bfv[nf] = *(const bfrag*)&Bl[((wn << 6) + (nf << 4) + fr) * 40 + (fg << 3)];
      #pragma unroll
      for (int mf = 0; mf < 4; ++mf)
        #pragma unroll
        for (int nf = 0; nf < 4; ++nf)
          acc[mf][nf] = __builtin_amdgcn_mfma_f32_16x16x32_bf16(af[mf], bfv[nf],
                                                                acc[mf][nf], 0, 0, 0);
    }
  }

  // epilogue: bias + relu -> bf16 NHWC interior
  #pragma unroll
  for (int nf = 0; nf < 4; ++nf) {
    int pp = p0 + (wn << 6) + (nf << 4) + fr;
    if (pp >= L.P) continue;
    int n2 = pp >> L.logHW;
    int y2 = (pp >> L.logW) & (L.H - 1);
    int x2 = pp & (L.W - 1);
    __bf16* ob = outb + L.act_off + (((n2 * (L.H + 2) + y2 + 1) * Wp + x2 + 1) << 8);
    #pragma unroll
    for (int mf = 0; mf < 4; ++mf) {
      int cob = m0 + (wm << 6) + (mf << 4) + (fg << 2);
      f32x4 bb = *(const f32x4*)(bias + cob);
      f32x4 v  = acc[mf][nf];
      bf4 ov;
      #pragma unroll
      for (int j = 0; j < 4; ++j) ov[j] = (__bf16)fmaxf(v[j] + bb[j], 0.0f);
      *(bf4*)(ob + cob) = ov;
    }
  }
}

// ---- out conv: 256->Cout (24 reg / 54 cls), +bias, scatter f32 to d_out ----
__global__ __launch_bounds__(256)
void conv_out_k(const __bf16* __restrict__ inb, const __bf16* __restrict__ wT,
                const float* __restrict__ biasO, float* __restrict__ dout,
                Desc d, int Cout, int isCls)
{
  __shared__ __bf16 Al[128 * 40];
  __shared__ __bf16 Bl[128 * 40];
  int b  = blockIdx.x;
  int li = 0;
  #pragma unroll
  for (int i = 1; i < 6; ++i) li = (b >= d.lv[i].blk_start) ? i : li;
  LevelD L = d.lv[li];
  int nt = b - L.blk_start;
  int p0 = nt << 7;
  int tid  = threadIdx.x;
  int lane = tid & 63;
  int wv   = tid >> 6;
  int wm = wv >> 1, wn = wv & 1;
  int fr = lane & 15, fg = lane >> 4;
  int Wp = L.W + 2;

  int sp = tid >> 1;
  int sc = (tid & 1) << 4;
  int p  = p0 + sp;
  bool pv = p < L.P;
  int pc = pv ? p : 0;
  int n  = pc >> L.logHW;
  int y  = (pc >> L.logW) & (L.H - 1);
  int x  = pc & (L.W - 1);
  const __bf16* bbase = inb + L.act_off + (((n * (L.H + 2) + y) * Wp + x) << 8) + sc;
  bool av = sp < Cout;
  const __bf16* abase = wT + sp * 2304 + sc;

  int mfN = (Cout - (wm << 6) + 15) >> 4;
  mfN = mfN < 0 ? 0 : (mfN > 4 ? 4 : mfN);

  f32x4 acc[4][4] = {};

  for (int t = 0; t < 9; ++t) {
    int ky = t / 3, kx = t - ky * 3;
    const __bf16* bt = bbase + ((ky * Wp + kx) << 8);
    const __bf16* at = abase + (t << 8);
    for (int c0 = 0; c0 < 256; c0 += 32) {
      i32x4 av0 = {}, av1 = {}, bv0 = {}, bv1 = {};
      if (av) {
        av0 = *(const i32x4*)(at + c0);
        av1 = *(const i32x4*)(at + c0 + 8);
      }
      if (pv) {
        bv0 = *(const i32x4*)(bt + c0);
        bv1 = *(const i32x4*)(bt + c0 + 8);
      }
      __syncthreads();
      *(i32x4*)&Al[sp * 40 + sc]     = av0;
      *(i32x4*)&Al[sp * 40 + sc + 8] = av1;
      *(i32x4*)&Bl[sp * 40 + sc]     = bv0;
      *(i32x4*)&Bl[sp * 40 + sc + 8] = bv1;
      __syncthreads();
      bfrag bfv[4];
      #pragma unroll
      for (int nf = 0; nf < 4; ++nf)
        bfv[nf] = *(const bfrag*)&Bl[((wn << 6) + (nf << 4) + fr) * 40 + (fg << 3)];
      #pragma unroll
      for (int mf = 0; mf < 4; ++mf) {
        if (mf < mfN) {
          bfrag af = *(const bfrag*)&Al[((wm << 6) + (mf << 4) + fr) * 40 + (fg << 3)];
          #pragma unroll
          for (int nf = 0; nf < 4; ++nf)
            acc[mf][nf] = __builtin_amdgcn_mfma_f32_16x16x32_bf16(af, bfv[nf],
                                                                  acc[mf][nf], 0, 0, 0);
        }
      }
    }
  }

  #pragma unroll
  for (int nf = 0; nf < 4; ++nf) {
    int pp = p0 + (wn << 6) + (nf << 4) + fr;
    if (pp >= L.P) continue;
    int n2 = pp >> L.logHW;
    int y2 = (pp >> L.logW) & (L.H - 1);
    int x2 = pp & (L.W - 1);
    int sp_off = L.aoff + y2 * L.W + x2;
    #pragma unroll
    for (int mf = 0; mf < 4; ++mf) {
      if (mf < mfN) {
        #pragma unroll
        for (int j = 0; j < 4; ++j) {
          int co = (wm << 6) + (mf << 4) + (fg << 2) + j;
          if (co < Cout) {
            float val = acc[mf][nf][j] + biasO[co];
            int g   = co / 6;
            int box = co - g * 6;
            size_t idx;
            if (isCls) idx = (size_t)CLS_BASE + ((size_t)n2 * 9 + g) * TOTAL_ANCH
                             + sp_off + box * L.HW;
            else       idx = ((size_t)n2 * 4 + g) * TOTAL_ANCH + sp_off + box * L.HW;
            dout[idx] = val;
          }
        }
      }
    }
  }
}

extern "C" void kernel_launch(void* const* d_in, const int* in_sizes, int n_in,
                              void* d_out, int out_size, void* d_ws, size_t ws_size,
                              hipStream_t stream) {
  if (ws_size < WS_ELEMS * 2) return;  // fail loud: output stays poisoned

  static const int kH[6]      = {32, 16, 8, 4, 2, 1};
  static const int kW[6]      = {256, 128, 64, 32, 16, 8};
  static const int kLogW[6]   = {8, 7, 6, 5, 4, 3};
  static const int kLogHW[6]  = {13, 11, 9, 7, 5, 3};
  static const int kActOff[6] = {0, 17965056, 22757376, 24109056, 24526848, 24674304};
  static const int kAoff[6]   = {0, 49152, 61440, 64512, 65280, 65472};
  static const int kNtn[6]    = {512, 128, 32, 8, 2, 1};
  static const int kBlkMid[6] = {0, 1024, 1280, 1344, 1360, 1364};
  static const int kBlkOut[6] = {0, 512, 640, 672, 680, 682};
  static const int kPosSt[6]  = {0, 65536, 81920, 86016, 87040, 87296};

  FPtrs fp;
  for (int i = 0; i < 6; ++i) fp.f[i] = (const float*)d_in[i];
  const float* reg_w  = (const float*)d_in[6];
  const float* reg_b  = (const float*)d_in[7];
  const float* reg_wo = (const float*)d_in[8];
  const float* reg_bo = (const float*)d_in[9];
  const float* cls_w  = (const float*)d_in[10];
  const float* cls_b  = (const float*)d_in[11];
  const float* cls_wo = (const float*)d_in[12];
  const float* cls_bo = (const float*)d_in[13];
  __bf16* ws = (__bf16*)d_ws;

  Desc dm, dо_unused; (void)dо_unused;
  Desc dmid, dout_d;
  for (int i = 0; i < 6; ++i) {
    LevelD L;
    L.H = kH[i]; L.W = kW[i]; L.logW = kLogW[i]; L.logHW = kLogHW[i];
    L.HW = kH[i] * kW[i]; L.P = 8 * L.HW;
    L.act_off = kActOff[i]; L.aoff = kAoff[i]; L.ntn = kNtn[i];
    L.pos_start = kPosSt[i];
    L.blk_start = kBlkMid[i];
    dmid.lv[i] = L;
    L.blk_start = kBlkOut[i];
    dout_d.lv[i] = L;
  }
  (void)dm;

  // zero both activation buffers (halos must be zero)
  hipMemsetAsync((char*)d_ws + (size_t)ACT0_OFF * 2, 0,
                 (size_t)ACT_ELEMS * 2 * 2, stream);

  prep_k<<<256, 256, 0, stream>>>(reg_w,  ws + WREG_OFF,  1024 * 2304);
  prep_k<<<256, 256, 0, stream>>>(cls_w,  ws + WCLS_OFF,  1024 * 2304);
  prep_k<<<64,  256, 0, stream>>>(reg_wo, ws + WREGO_OFF, 24 * 2304);
  prep_k<<<64,  256, 0, stream>>>(cls_wo, ws + WCLSO_OFF, 54 * 2304);

  for (int head = 0; head < 2; ++head) {
    convert_k<<<5460, 256, 0, stream>>>(fp, ws + ACT0_OFF, dmid);
    const __bf16* wT = ws + (head ? WCLS_OFF : WREG_OFF);
    const float*  bb = head ? cls_b : reg_b;
    conv_mid_k<<<1366, 256, 0, stream>>>(ws + ACT0_OFF, ws + ACT1_OFF, wT + 0 * 589824, bb + 0,   dmid);
    conv_mid_k<<<1366, 256, 0, stream>>>(ws + ACT1_OFF, ws + ACT0_OFF, wT + 1 * 589824, bb + 256, dmid);
    conv_mid_k<<<1366, 256, 0, stream>>>(ws + ACT0_OFF, ws + ACT1_OFF, wT + 2 * 589824, bb + 512, dmid);
    conv_mid_k<<<1366, 256, 0, stream>>>(ws + ACT1_OFF, ws + ACT0_OFF, wT + 3 * 589824, bb + 768, dmid);
    conv_out_k<<<683, 256, 0, stream>>>(ws + ACT0_OFF,
        ws + (head ? WCLSO_OFF : WREGO_OFF), head ? cls_bo : reg_bo,
        (float*)d_out, dout_d, head ? 54 : 24, head);
  }
}

// Round 2
// 1542.517 us; speedup vs baseline: 1.0641x; 1.0641x over previous
//
#include <hip/hip_runtime.h>
#include <hip/hip_bf16.h>

// RetinaNet head on MI355X: implicit-GEMM bf16 MFMA convs over padded-NHWC
// activations. R2: global_load_lds(16B) staging, double-buffered LDS,
// 1 barrier/K-step, XOR slot-swizzle (source+read side, linear LDS dest).

typedef float  f32x4 __attribute__((ext_vector_type(4)));
typedef int    i32x4 __attribute__((ext_vector_type(4)));
typedef __bf16 bfrag __attribute__((ext_vector_type(8)));
typedef __bf16 bf4   __attribute__((ext_vector_type(4)));

struct LevelD {
  int H, W, logW, logHW, P, HW, act_off, aoff, ntn, blk_start, pos_start;
};
struct Desc  { LevelD lv[6]; };
struct FPtrs { const float* f[6]; };

#define ACT_ELEMS  24735744
#define WREG_OFF   0
#define WCLS_OFF   2359296
#define WREGO_OFF  4718592
#define WCLSO_OFF  4773888
#define ACT0_OFF   4898304
#define ACT1_OFF   29634048
#define WS_ELEMS   54369792ull
#define TOTAL_ANCH 65520
#define CLS_BASE   2096640

__device__ __forceinline__ void glds16(const __bf16* g, __bf16* l) {
  __builtin_amdgcn_global_load_lds(
      (const __attribute__((address_space(1))) void*)g,
      (__attribute__((address_space(3))) void*)l, 16, 0, 0);
}

// ---- weight prep: [CO][256ci][3][3] f32 -> [CO][t=9][256ci] bf16 ----
__global__ __launch_bounds__(256) void prep_k(const float* __restrict__ w,
                                              __bf16* __restrict__ o, int total)
{
  for (int i = blockIdx.x * 256 + threadIdx.x; i < total; i += gridDim.x * 256) {
    int co = i / 2304;
    int r  = i - co * 2304;
    int t  = r >> 8;
    int ci = r & 255;
    o[i] = (__bf16)w[((co << 8) + ci) * 9 + t];
  }
}

// ---- NCHW f32 feat -> padded NHWC bf16 (interior only; halos pre-zeroed) ----
__global__ __launch_bounds__(256) void convert_k(FPtrs fp, __bf16* __restrict__ act, Desc d)
{
  __shared__ __bf16 T[16 * 264];
  int b  = blockIdx.x;
  int p0 = b << 4;
  int li = 0;
  #pragma unroll
  for (int i = 1; i < 6; ++i) li = (p0 >= d.lv[i].pos_start) ? i : li;
  LevelD L = d.lv[li];
  int lp  = p0 - L.pos_start;
  int tid = threadIdx.x;
  int pl = tid & 15;
  int p  = lp + pl;
  int n  = p >> L.logHW;
  int y  = (p >> L.logW) & (L.H - 1);
  int x  = p & (L.W - 1);
  const float* src = fp.f[li];
  size_t base = (size_t)n * ((size_t)L.HW << 8) + (size_t)y * L.W + x;
  int c0 = tid >> 4;
  #pragma unroll
  for (int it = 0; it < 16; ++it) {
    int c = c0 + (it << 4);
    T[pl * 264 + c] = (__bf16)src[base + (size_t)c * L.HW];
  }
  __syncthreads();
  int p2 = tid >> 4;
  int cc = (tid & 15) << 4;
  int pg = lp + p2;
  int n2 = pg >> L.logHW;
  int y2 = (pg >> L.logW) & (L.H - 1);
  int x2 = pg & (L.W - 1);
  __bf16* dst = act + L.act_off +
      ((size_t)((n2 * (L.H + 2) + y2 + 1) * (L.W + 2) + x2 + 1) << 8) + cc;
  i32x4 v0 = *(const i32x4*)&T[p2 * 264 + cc];
  i32x4 v1 = *(const i32x4*)&T[p2 * 264 + cc + 8];
  *(i32x4*)dst       = v0;
  *(i32x4*)(dst + 8) = v1;
}

// ---- mid conv: 256->256, +bias, ReLU ----
// 128x128 tile, BK=32, 4 waves (2x2), dbuf LDS via global_load_lds width=16.
__global__ __launch_bounds__(256)
void conv_mid_k(const __bf16* __restrict__ inb, __bf16* __restrict__ outb,
                const __bf16* __restrict__ wT, const float* __restrict__ bias,
                Desc d)
{
  __shared__ __bf16 Al[2][128 * 32];   // linear [co][ci32], 64B rows
  __shared__ __bf16 Bl[2][128 * 32];   // linear [pos][ci32]
  int b  = blockIdx.x;
  int li = 0;
  #pragma unroll
  for (int i = 1; i < 6; ++i) li = (b >= d.lv[i].blk_start) ? i : li;
  LevelD L  = d.lv[li];
  int local = b - L.blk_start;
  int mt = local & 1;
  int nt = local >> 1;
  int m0 = mt << 7;
  int p0 = nt << 7;
  int tid  = threadIdx.x;
  int lane = tid & 63;
  int wv   = tid >> 6;
  int wm = wv >> 1, wn = wv & 1;
  int fr = lane & 15, fg = lane >> 4;
  int Wp = L.W + 2;

  // staging decode: wave wv covers rows wv*16 + r*64 (r=0,1), lane -> (rsub, slot)
  int rsub = lane >> 2;
  int slot = lane & 3;
  int sw   = slot ^ ((rsub >> 1) & 3);          // XOR slot-swizzle (source side)

  const __bf16* gA[2];
  const __bf16* gB[2];
  int ldsA[2], ldsB[2];
  #pragma unroll
  for (int r = 0; r < 2; ++r) {
    int row = (r << 6) + (wv << 4) + rsub;
    gA[r] = wT + (m0 + row) * 2304 + (sw << 3);
    int p  = p0 + row;
    int pc = (p < L.P) ? p : 0;
    int n  = pc >> L.logHW;
    int y  = (pc >> L.logW) & (L.H - 1);
    int x  = pc & (L.W - 1);
    gB[r] = inb + L.act_off + (((n * (L.H + 2) + y) * Wp + x) << 8) + (sw << 3);
    ldsA[r] = ((r << 6) + (wv << 4)) << 5;      // row*32 elems, wave base
    ldsB[r] = ldsA[r];
  }

  // fragment read offsets (swizzled column)
  int csw = ((fg ^ ((fr >> 1) & 3)) << 3);
  int offA[4], offB[4];
  #pragma unroll
  for (int f = 0; f < 4; ++f) {
    offA[f] = (((wm << 6) + (f << 4) + fr) << 5) + csw;
    offB[f] = (((wn << 6) + (f << 4) + fr) << 5) + csw;
  }

  auto stage = [&](int k, int bb) {
    int t  = k >> 3;
    int c0 = (k & 7) << 5;
    int ky = (t >= 6) ? 2 : (t >= 3 ? 1 : 0);
    int kx = t - ky * 3;
    int koffA = (t << 8) + c0;
    int koffB = ((ky * Wp + kx) << 8) + c0;
    glds16(gA[0] + koffA, &Al[bb][ldsA[0]]);
    glds16(gA[1] + koffA, &Al[bb][ldsA[1]]);
    glds16(gB[0] + koffB, &Bl[bb][ldsB[0]]);
    glds16(gB[1] + koffB, &Bl[bb][ldsB[1]]);
  };

  f32x4 acc[4][4] = {};

  stage(0, 0);
  __syncthreads();
  for (int k = 0; k < 72; ++k) {
    int cur = k & 1;
    if (k < 71) stage(k + 1, cur ^ 1);
    bfrag af[4], bfv[4];
    #pragma unroll
    for (int mf = 0; mf < 4; ++mf) af[mf]  = *(const bfrag*)&Al[cur][offA[mf]];
    #pragma unroll
    for (int nf = 0; nf < 4; ++nf) bfv[nf] = *(const bfrag*)&Bl[cur][offB[nf]];
    #pragma unroll
    for (int mf = 0; mf < 4; ++mf)
      #pragma unroll
      for (int nf = 0; nf < 4; ++nf)
        acc[mf][nf] = __builtin_amdgcn_mfma_f32_16x16x32_bf16(af[mf], bfv[nf],
                                                              acc[mf][nf], 0, 0, 0);
    __syncthreads();
  }

  // epilogue: bias + relu -> bf16 NHWC interior
  #pragma unroll
  for (int nf = 0; nf < 4; ++nf) {
    int pp = p0 + (wn << 6) + (nf << 4) + fr;
    if (pp >= L.P) continue;
    int n2 = pp >> L.logHW;
    int y2 = (pp >> L.logW) & (L.H - 1);
    int x2 = pp & (L.W - 1);
    __bf16* ob = outb + L.act_off + (((n2 * (L.H + 2) + y2 + 1) * Wp + x2 + 1) << 8);
    #pragma unroll
    for (int mf = 0; mf < 4; ++mf) {
      int cob = m0 + (wm << 6) + (mf << 4) + (fg << 2);
      f32x4 bb = *(const f32x4*)(bias + cob);
      f32x4 v  = acc[mf][nf];
      bf4 ov;
      #pragma unroll
      for (int j = 0; j < 4; ++j) ov[j] = (__bf16)fmaxf(v[j] + bb[j], 0.0f);
      *(bf4*)(ob + cob) = ov;
    }
  }
}

// ---- out conv: 256->Cout (24 reg / 54 cls), +bias, scatter f32 to d_out ----
__global__ __launch_bounds__(256)
void conv_out_k(const __bf16* __restrict__ inb, const __bf16* __restrict__ wT,
                const float* __restrict__ biasO, float* __restrict__ dout,
                Desc d, int Cout, int isCls)
{
  __shared__ __bf16 Al[2][128 * 32];
  __shared__ __bf16 Bl[2][128 * 32];
  int b  = blockIdx.x;
  int li = 0;
  #pragma unroll
  for (int i = 1; i < 6; ++i) li = (b >= d.lv[i].blk_start) ? i : li;
  LevelD L = d.lv[li];
  int nt = b - L.blk_start;
  int p0 = nt << 7;
  int tid  = threadIdx.x;
  int lane = tid & 63;
  int wv   = tid >> 6;
  int wm = wv >> 1, wn = wv & 1;
  int fr = lane & 15, fg = lane >> 4;
  int Wp = L.W + 2;

  int rsub = lane >> 2;
  int slot = lane & 3;
  int sw   = slot ^ ((rsub >> 1) & 3);

  const __bf16* gA[2];
  const __bf16* gB[2];
  int ldsA[2];
  #pragma unroll
  for (int r = 0; r < 2; ++r) {
    int row = (r << 6) + (wv << 4) + rsub;
    int co  = (row < Cout) ? row : 0;           // clamp dead rows to valid mem
    gA[r] = wT + co * 2304 + (sw << 3);
    int p  = p0 + row;
    int pc = (p < L.P) ? p : 0;
    int n  = pc >> L.logHW;
    int y  = (pc >> L.logW) & (L.H - 1);
    int x  = pc & (L.W - 1);
    gB[r] = inb + L.act_off + (((n * (L.H + 2) + y) * Wp + x) << 8) + (sw << 3);
    ldsA[r] = ((r << 6) + (wv << 4)) << 5;
  }

  int csw = ((fg ^ ((fr >> 1) & 3)) << 3);
  int offA[4], offB[4];
  #pragma unroll
  for (int f = 0; f < 4; ++f) {
    offA[f] = (((wm << 6) + (f << 4) + fr) << 5) + csw;
    offB[f] = (((wn << 6) + (f << 4) + fr) << 5) + csw;
  }

  int mfN = (Cout - (wm << 6) + 15) >> 4;
  mfN = mfN < 0 ? 0 : (mfN > 4 ? 4 : mfN);

  auto stage = [&](int k, int bb) {
    int t  = k >> 3;
    int c0 = (k & 7) << 5;
    int ky = (t >= 6) ? 2 : (t >= 3 ? 1 : 0);
    int kx = t - ky * 3;
    int koffA = (t << 8) + c0;
    int koffB = ((ky * Wp + kx) << 8) + c0;
    glds16(gA[0] + koffA, &Al[bb][ldsA[0]]);
    glds16(gA[1] + koffA, &Al[bb][ldsA[1]]);
    glds16(gB[0] + koffB, &Bl[bb][ldsA[0]]);
    glds16(gB[1] + koffB, &Bl[bb][ldsA[1]]);
  };

  f32x4 acc[4][4] = {};

  stage(0, 0);
  __syncthreads();
  for (int k = 0; k < 72; ++k) {
    int cur = k & 1;
    if (k < 71) stage(k + 1, cur ^ 1);
    bfrag bfv[4];
    #pragma unroll
    for (int nf = 0; nf < 4; ++nf) bfv[nf] = *(const bfrag*)&Bl[cur][offB[nf]];
    #pragma unroll
    for (int mf = 0; mf < 4; ++mf) {
      if (mf < mfN) {
        bfrag af = *(const bfrag*)&Al[cur][offA[mf]];
        #pragma unroll
        for (int nf = 0; nf < 4; ++nf)
          acc[mf][nf] = __builtin_amdgcn_mfma_f32_16x16x32_bf16(af, bfv[nf],
                                                                acc[mf][nf], 0, 0, 0);
      }
    }
    __syncthreads();
  }

  #pragma unroll
  for (int nf = 0; nf < 4; ++nf) {
    int pp = p0 + (wn << 6) + (nf << 4) + fr;
    if (pp >= L.P) continue;
    int n2 = pp >> L.logHW;
    int y2 = (pp >> L.logW) & (L.H - 1);
    int x2 = pp & (L.W - 1);
    int sp_off = L.aoff + y2 * L.W + x2;
    #pragma unroll
    for (int mf = 0; mf < 4; ++mf) {
      if (mf < mfN) {
        #pragma unroll
        for (int j = 0; j < 4; ++j) {
          int co = (wm << 6) + (mf << 4) + (fg << 2) + j;
          if (co < Cout) {
            float val = acc[mf][nf][j] + biasO[co];
            int g   = co / 6;
            int box = co - g * 6;
            size_t idx;
            if (isCls) idx = (size_t)CLS_BASE + ((size_t)n2 * 9 + g) * TOTAL_ANCH
                             + sp_off + box * L.HW;
            else       idx = ((size_t)n2 * 4 + g) * TOTAL_ANCH + sp_off + box * L.HW;
            dout[idx] = val;
          }
        }
      }
    }
  }
}

extern "C" void kernel_launch(void* const* d_in, const int* in_sizes, int n_in,
                              void* d_out, int out_size, void* d_ws, size_t ws_size,
                              hipStream_t stream) {
  if (ws_size < WS_ELEMS * 2) return;  // fail loud: output stays poisoned

  static const int kH[6]      = {32, 16, 8, 4, 2, 1};
  static const int kW[6]      = {256, 128, 64, 32, 16, 8};
  static const int kLogW[6]   = {8, 7, 6, 5, 4, 3};
  static const int kLogHW[6]  = {13, 11, 9, 7, 5, 3};
  static const int kActOff[6] = {0, 17965056, 22757376, 24109056, 24526848, 24674304};
  static const int kAoff[6]   = {0, 49152, 61440, 64512, 65280, 65472};
  static const int kNtn[6]    = {512, 128, 32, 8, 2, 1};
  static const int kBlkMid[6] = {0, 1024, 1280, 1344, 1360, 1364};
  static const int kBlkOut[6] = {0, 512, 640, 672, 680, 682};
  static const int kPosSt[6]  = {0, 65536, 81920, 86016, 87040, 87296};

  FPtrs fp;
  for (int i = 0; i < 6; ++i) fp.f[i] = (const float*)d_in[i];
  const float* reg_w  = (const float*)d_in[6];
  const float* reg_b  = (const float*)d_in[7];
  const float* reg_wo = (const float*)d_in[8];
  const float* reg_bo = (const float*)d_in[9];
  const float* cls_w  = (const float*)d_in[10];
  const float* cls_b  = (const float*)d_in[11];
  const float* cls_wo = (const float*)d_in[12];
  const float* cls_bo = (const float*)d_in[13];
  __bf16* ws = (__bf16*)d_ws;

  Desc dmid, dout_d;
  for (int i = 0; i < 6; ++i) {
    LevelD L;
    L.H = kH[i]; L.W = kW[i]; L.logW = kLogW[i]; L.logHW = kLogHW[i];
    L.HW = kH[i] * kW[i]; L.P = 8 * L.HW;
    L.act_off = kActOff[i]; L.aoff = kAoff[i]; L.ntn = kNtn[i];
    L.pos_start = kPosSt[i];
    L.blk_start = kBlkMid[i];
    dmid.lv[i] = L;
    L.blk_start = kBlkOut[i];
    dout_d.lv[i] = L;
  }

  // zero both activation buffers (halos must be zero)
  hipMemsetAsync((char*)d_ws + (size_t)ACT0_OFF * 2, 0,
                 (size_t)ACT_ELEMS * 2 * 2, stream);

  prep_k<<<256, 256, 0, stream>>>(reg_w,  ws + WREG_OFF,  1024 * 2304);
  prep_k<<<256, 256, 0, stream>>>(cls_w,  ws + WCLS_OFF,  1024 * 2304);
  prep_k<<<64,  256, 0, stream>>>(reg_wo, ws + WREGO_OFF, 24 * 2304);
  prep_k<<<64,  256, 0, stream>>>(cls_wo, ws + WCLSO_OFF, 54 * 2304);

  for (int head = 0; head < 2; ++head) {
    convert_k<<<5460, 256, 0, stream>>>(fp, ws + ACT0_OFF, dmid);
    const __bf16* wT = ws + (head ? WCLS_OFF : WREG_OFF);
    const float*  bb = head ? cls_b : reg_b;
    conv_mid_k<<<1366, 256, 0, stream>>>(ws + ACT0_OFF, ws + ACT1_OFF, wT + 0 * 589824, bb + 0,   dmid);
    conv_mid_k<<<1366, 256, 0, stream>>>(ws + ACT1_OFF, ws + ACT0_OFF, wT + 1 * 589824, bb + 256, dmid);
    conv_mid_k<<<1366, 256, 0, stream>>>(ws + ACT0_OFF, ws + ACT1_OFF, wT + 2 * 589824, bb + 512, dmid);
    conv_mid_k<<<1366, 256, 0, stream>>>(ws + ACT1_OFF, ws + ACT0_OFF, wT + 3 * 589824, bb + 768, dmid);
    conv_out_k<<<683, 256, 0, stream>>>(ws + ACT0_OFF,
        ws + (head ? WCLSO_OFF : WREGO_OFF), head ? cls_bo : reg_bo,
        (float*)d_out, dout_d, head ? 54 : 24, head);
  }
}